// Round 8
// baseline (204.404 us; speedup 1.0000x reference)
//
#include <hip/hip_runtime.h>

typedef _Float16 f16x8 __attribute__((ext_vector_type(8)));
typedef _Float16 f16x4 __attribute__((ext_vector_type(4)));
typedef float    f32x4 __attribute__((ext_vector_type(4)));

static constexpr int BATCH = 32;
static constexpr int CDIM  = 256;    // C
static constexpr int HW    = 4096;   // h (= A_H = K of GEMM1)
static constexpr int AW    = 1024;   // A rows (w)
static constexpr int AH    = 4096;   // A cols (h)
static constexpr int BW    = 256;    // B rows (c)
static constexpr int BH    = 512;    // B cols (d)
static constexpr int CAND_CAP = 8192;

// scratch u32 layout (relative to scratch base)
// 0     histA0[4096]   4096  histA1[4096]
// 8192  histB0[4096]   12288 histB1[4096]
// 16384 selA[8]  ([3]=target2 [4]=vcut [5]=cutIdx [6]=candCount)
// 16392 selB[8]
// 16400 candBitsA[8192]  24592 candIdxA[8192]
// 32784 candBitsB[8192]  40976 candIdxB[8192]
static constexpr int MEMSET_U32 = 16400;
static constexpr int SCRATCH_U32_TOTAL = 49168;

__device__ __forceinline__ void gload16(const void* g, void* l) {
    __builtin_amdgcn_global_load_lds((const __attribute__((address_space(1))) void*)g,
                                     (__attribute__((address_space(3))) void*)l, 16, 0, 0);
}

// every block computes the same select result from a global 4096-bin histogram.
__device__ void select_bin_inline(const unsigned* __restrict__ hist, unsigned target,
                                  unsigned* shp /*[256]*/, unsigned* res /*[2]*/) {
    const int t = threadIdx.x;
    unsigned sum = 0;
    #pragma unroll
    for (int k = 0; k < 16; ++k) sum += hist[t * 16 + k];
    shp[t] = sum;
    __syncthreads();
    if (t == 0) {
        unsigned c = 0; int k = 0;
        while (c + shp[k] <= target) { c += shp[k]; ++k; }
        int b = k * 16;
        while (true) { unsigned h = hist[b]; if (target < c + h) break; c += h; ++b; }
        res[0] = (unsigned)b; res[1] = c;
    }
    __syncthreads();
}

// ---------------- pass 0: hist of key>>19 (12 bits) + fused x f32->f16 conversion ----------------
// blockIdx.y: 0 = hist(sA), 1 = hist(sB), 2..3 = stream-convert x to xf16 (2x parallel slabs).
__global__ void hist0_cvt_kernel(const float* __restrict__ sA, int nA,
                                 const float* __restrict__ sB, int nB,
                                 const float* __restrict__ x, _Float16* __restrict__ xf, int nx8,
                                 unsigned* __restrict__ scratch) {
    __shared__ unsigned lh[4][4096];
    const int y = blockIdx.y;
    const int t = threadIdx.x;
    if (y >= 2) {
        int vb = (y - 2) * gridDim.x + blockIdx.x;       // virtual block 0..2*gridDim.x-1
        int stride = 2 * gridDim.x * 256;
        for (int i = vb * 256 + t; i < nx8; i += stride) {
            f32x4 v0 = reinterpret_cast<const f32x4*>(x)[i * 2];
            f32x4 v1 = reinterpret_cast<const f32x4*>(x)[i * 2 + 1];
            f16x8 h = { (_Float16)v0[0], (_Float16)v0[1], (_Float16)v0[2], (_Float16)v0[3],
                        (_Float16)v1[0], (_Float16)v1[1], (_Float16)v1[2], (_Float16)v1[3] };
            reinterpret_cast<f16x8*>(xf)[i] = h;
        }
        return;
    }
    const float* s = y ? sB : sA;
    const int n4 = (y ? nB : nA) >> 2;
    unsigned* hist = scratch + (y ? 8192 : 0);
    const int wave = t >> 6;
    for (int i = t; i < 4 * 4096; i += 256) ((unsigned*)lh)[i] = 0;
    __syncthreads();
    for (int i = blockIdx.x * 256 + t; i < n4; i += gridDim.x * 256) {
        float4 v = reinterpret_cast<const float4*>(s)[i];
        atomicAdd(&lh[wave][(__float_as_uint(v.x) & 0x7fffffffu) >> 19], 1u);
        atomicAdd(&lh[wave][(__float_as_uint(v.y) & 0x7fffffffu) >> 19], 1u);
        atomicAdd(&lh[wave][(__float_as_uint(v.z) & 0x7fffffffu) >> 19], 1u);
        atomicAdd(&lh[wave][(__float_as_uint(v.w) & 0x7fffffffu) >> 19], 1u);
    }
    __syncthreads();
    for (int b = t; b < 4096; b += 256) {
        unsigned v = lh[0][b] + lh[1][b] + lh[2][b] + lh[3][b];
        if (v) atomicAdd(&hist[b], v);
    }
}

// ---------------- pass 1: inline select0, hist of (key>>7)&4095 among prefix matches ----------------
__global__ void hist1_kernel(const float* __restrict__ sA, int nA, unsigned jA,
                             const float* __restrict__ sB, int nB, unsigned jB,
                             unsigned* __restrict__ scratch) {
    __shared__ unsigned lh[4][4096];
    __shared__ unsigned shp[256];
    __shared__ unsigned res[2];
    const int y = blockIdx.y;
    const float* s = y ? sB : sA;
    const int n4 = (y ? nB : nA) >> 2;
    const unsigned j = y ? jB : jA;
    const unsigned* hist0 = scratch + (y ? 8192 : 0);
    unsigned* hist1 = scratch + 4096 + (y ? 8192 : 0);
    const int t = threadIdx.x;
    const int wave = t >> 6;
    for (int i = t; i < 4 * 4096; i += 256) ((unsigned*)lh)[i] = 0;
    select_bin_inline(hist0, j, shp, res);       // includes syncthreads
    const unsigned bin0 = res[0];
    for (int i = blockIdx.x * 256 + t; i < n4; i += gridDim.x * 256) {
        float4 v = reinterpret_cast<const float4*>(s)[i];
        unsigned k0 = __float_as_uint(v.x) & 0x7fffffffu;
        unsigned k1 = __float_as_uint(v.y) & 0x7fffffffu;
        unsigned k2 = __float_as_uint(v.z) & 0x7fffffffu;
        unsigned k3 = __float_as_uint(v.w) & 0x7fffffffu;
        if ((k0 >> 19) == bin0) atomicAdd(&lh[wave][(k0 >> 7) & 4095], 1u);
        if ((k1 >> 19) == bin0) atomicAdd(&lh[wave][(k1 >> 7) & 4095], 1u);
        if ((k2 >> 19) == bin0) atomicAdd(&lh[wave][(k2 >> 7) & 4095], 1u);
        if ((k3 >> 19) == bin0) atomicAdd(&lh[wave][(k3 >> 7) & 4095], 1u);
    }
    __syncthreads();
    for (int b = t; b < 4096; b += 256) {
        unsigned v = lh[0][b] + lh[1][b] + lh[2][b] + lh[3][b];
        if (v) atomicAdd(&hist1[b], v);
    }
}

// ---------------- extract: inline select0+select1, gather candidates with 24-bit prefix ----------------
__global__ void extract_kernel(const float* __restrict__ sA, int nA, unsigned jA,
                               const float* __restrict__ sB, int nB, unsigned jB,
                               unsigned* __restrict__ scratch) {
    __shared__ unsigned shp[256];
    __shared__ unsigned res0[2], res1[2];
    const int y = blockIdx.y;
    const float* s = y ? sB : sA;
    const int n4 = (y ? nB : nA) >> 2;
    const unsigned j = y ? jB : jA;
    const unsigned* hist0 = scratch + (y ? 8192 : 0);
    const unsigned* hist1 = scratch + 4096 + (y ? 8192 : 0);
    unsigned* sel = scratch + 16384 + y * 8;
    unsigned* candBits = scratch + (y ? 32784 : 16400);
    unsigned* candIdx  = candBits + CAND_CAP;
    const int t = threadIdx.x;
    select_bin_inline(hist0, j, shp, res0);
    select_bin_inline(hist1, j - res0[1], shp, res1);
    const unsigned pref = (res0[0] << 12) | res1[0];
    const unsigned base2 = res0[1] + res1[1];
    if (blockIdx.x == 0 && t == 0) sel[3] = j - base2;   // rank within candidate set
    for (int i = blockIdx.x * 256 + t; i < n4; i += gridDim.x * 256) {
        float4 v = reinterpret_cast<const float4*>(s)[i];
        #pragma unroll
        for (int k = 0; k < 4; ++k) {
            unsigned bits = __float_as_uint(k == 0 ? v.x : k == 1 ? v.y : k == 2 ? v.z : v.w) & 0x7fffffffu;
            if ((bits >> 7) == pref) {
                unsigned p = atomicAdd(&sel[6], 1u);
                if (p < CAND_CAP) { candBits[p] = bits; candIdx[p] = (unsigned)(i * 4 + k); }
            }
        }
    }
}

// ---------------- finalize: exact (value, index)-lexicographic rank among candidates ----------------
__global__ void finalize_kernel(unsigned* __restrict__ scratch) {
    __shared__ unsigned sb[CAND_CAP];
    __shared__ unsigned si[CAND_CAP];
    const int y = blockIdx.y;
    unsigned* sel = scratch + 16384 + y * 8;
    const unsigned* candBits = scratch + (y ? 32784 : 16400);
    const unsigned* candIdx  = candBits + CAND_CAP;
    const int t = threadIdx.x;
    unsigned cnt = sel[6]; if (cnt > CAND_CAP) cnt = CAND_CAP;
    const unsigned target = sel[3];
    for (unsigned c = t; c < cnt; c += 256) { sb[c] = candBits[c]; si[c] = candIdx[c]; }
    __syncthreads();
    for (unsigned c = t; c < cnt; c += 256) {
        unsigned b = sb[c], ix = si[c];
        unsigned r = 0;
        for (unsigned q = 0; q < cnt; ++q)
            r += (sb[q] < b) || (sb[q] == b && si[q] < ix);
        if (r == target) { sel[4] = b; sel[5] = ix; }
    }
}

// ---------------- apply: branchless mask + masked-f16 write + f32 pass-through copy ----------------
__global__ void apply_kernel(const float* __restrict__ sA, const float* __restrict__ wA,
                             _Float16* __restrict__ Am, float* __restrict__ wcopyA,
                             const float* __restrict__ sB, const float* __restrict__ wB,
                             _Float16* __restrict__ BmT, float* __restrict__ wcopyB,
                             int nA, int nB, const unsigned* __restrict__ scratch) {
    const int y = blockIdx.y;
    const float* s = y ? sB : sA;
    const float* w = y ? wB : wA;
    float* wcopy = y ? wcopyB : wcopyA;
    const int n4 = (y ? nB : nA) >> 2;
    const unsigned* sel = scratch + 16384 + y * 8;
    const unsigned vcut = sel[4], cutIdx = sel[5];
    const int t = threadIdx.x;
    for (int i = blockIdx.x * 256 + t; i < n4; i += gridDim.x * 256) {
        float4 sv = reinterpret_cast<const float4*>(s)[i];
        float4 wv = reinterpret_cast<const float4*>(w)[i];
        reinterpret_cast<float4*>(wcopy)[i] = wv;
        unsigned idx0 = (unsigned)i * 4;
        float m[4];
        #pragma unroll
        for (int k = 0; k < 4; ++k) {
            unsigned bits = __float_as_uint(k == 0 ? sv.x : k == 1 ? sv.y : k == 2 ? sv.z : sv.w) & 0x7fffffffu;
            bool keep = (bits > vcut) || (bits == vcut && (idx0 + k) >= cutIdx);
            m[k] = keep ? 1.0f : 0.0f;
        }
        if (!y) {
            f16x4 o = { (_Float16)(wv.x * m[0]), (_Float16)(wv.y * m[1]),
                        (_Float16)(wv.z * m[2]), (_Float16)(wv.w * m[3]) };
            *reinterpret_cast<f16x4*>(Am + idx0) = o;
        } else {
            int c = (int)(idx0 >> 9);           // row of B_ref [256][512]
            int d = (int)(idx0 & 511);
            BmT[(size_t)(d + 0) * BW + c] = (_Float16)(wv.x * m[0]);
            BmT[(size_t)(d + 1) * BW + c] = (_Float16)(wv.y * m[1]);
            BmT[(size_t)(d + 2) * BW + c] = (_Float16)(wv.z * m[2]);
            BmT[(size_t)(d + 3) * BW + c] = (_Float16)(wv.w * m[3]);
        }
    }
}

// ================= FUSED GEMM: out[b][w][d] = sum_c (sum_h Am[w][h]*xf[b][c][h]) * BmT[d][c] =====
// 512 blocks = (b, 64-row w-tile). Main loop: m97-exact 2-barrier, As[64][64]+Xs[256][64] via
// global_load_lds (pre-swizzled source). T[64][256] f16 parked in LDS (overlays dead staging),
// then mini-GEMM K=256 with BmT B-fragments read from L2-resident global. No temp in HBM.
// XCD-local: XCD k owns b in [4k,4k+4); 16 w-tiles per b run consecutively on that XCD.
__global__ __launch_bounds__(256, 2) void gemm_fused_kernel(
        const _Float16* __restrict__ Am,   // [1024][4096] f16
        const _Float16* __restrict__ xf,   // [32][256][4096] f16
        const _Float16* __restrict__ BmT,  // [512][256] f16
        float* __restrict__ out) {         // [32][1024][512] f32
    __shared__ __align__(16) char lds[40960];   // As 8K @0, Xs 32K @8192; T 32K overlays @0
    char* As = lds;
    char* Xs = lds + 8192;
    char* T  = lds;
    const int t = threadIdx.x;
    const int lane = t & 63;
    const int wave = t >> 6;               // 0..3
    const int xcd = blockIdx.x & 7;
    const int seq = blockIdx.x >> 3;       // 0..63
    const int b   = xcd * 4 + (seq >> 4);  // batch 0..31
    const int wt  = seq & 15;              // w-tile (64 rows)

    // staging: A 512 chunks (2/thread), X 2048 chunks (8/thread); rows advance by 32 per i.
    const int sRow = t >> 3;               // 0..31, + i*32
    const int sKk  = (t & 7) ^ (sRow & 7); // inverse-swizzled source (i*32 keeps row&7)
    const _Float16* aSrc = Am + ((size_t)wt * 64 + sRow) * HW + sKk * 8;
    const _Float16* xSrc = xf + ((size_t)b * 256 + sRow) * HW + sKk * 8;

    f32x4 acc[4][4] = {};
    const int wc = wave * 64;              // c-quadrant of this wave

    for (int kt = 0; kt < HW; kt += 64) {
        __syncthreads();
        #pragma unroll
        for (int i = 0; i < 2; ++i)
            gload16(aSrc + kt + (size_t)i * 32 * HW, As + i * 4096 + t * 16);
        #pragma unroll
        for (int i = 0; i < 8; ++i)
            gload16(xSrc + kt + (size_t)i * 32 * HW, Xs + i * 4096 + t * 16);
        __syncthreads();
        #pragma unroll
        for (int k2 = 0; k2 < 2; ++k2) {
            f16x8 af[4], bf[4];
            int kByte = k2 * 64 + (lane >> 4) * 16;
            #pragma unroll
            for (int mi = 0; mi < 4; ++mi) {
                int row = mi * 16 + (lane & 15);                       // w-row 0..63
                af[mi] = *(const f16x8*)(As + ((row * 128 + kByte) ^ ((row & 7) << 4)));
            }
            #pragma unroll
            for (int ni = 0; ni < 4; ++ni) {
                int row = wc + ni * 16 + (lane & 15);                  // c-row 0..255
                bf[ni] = *(const f16x8*)(Xs + ((row * 128 + kByte) ^ ((row & 7) << 4)));
            }
            #pragma unroll
            for (int mi = 0; mi < 4; ++mi)
                #pragma unroll
                for (int ni = 0; ni < 4; ++ni)
                    acc[mi][ni] = __builtin_amdgcn_mfma_f32_16x16x32_f16(af[mi], bf[ni], acc[mi][ni], 0, 0, 0);
        }
    }
    __syncthreads();   // all LDS reads done before T overlays the staging buffers

    // park acc -> T[64][256] f16 (rows 512B, XOR swizzle ((row&7)<<4))
    #pragma unroll
    for (int mi = 0; mi < 4; ++mi)
        #pragma unroll
        for (int ni = 0; ni < 4; ++ni)
            #pragma unroll
            for (int r = 0; r < 4; ++r) {
                int row = mi * 16 + ((lane >> 4) << 2) + r;            // w 0..63
                int col = wc + ni * 16 + (lane & 15);                  // c 0..255
                *(_Float16*)(T + ((row * 512 + col * 2) ^ ((row & 7) << 4))) = (_Float16)acc[mi][ni][r];
            }
    __syncthreads();

    // mini-GEMM: out[b][wt*64+w][d] = sum_c T[w][c] * BmT[d][c]; wave owns 128-d quadrant
    const int wd = wave * 128;
    f32x4 acc2[4][8] = {};
    #pragma unroll
    for (int ks = 0; ks < 8; ++ks) {
        f16x8 af2[4], bf2[8];
        int kByte = ks * 64 + (lane >> 4) * 16;
        #pragma unroll
        for (int mi = 0; mi < 4; ++mi) {
            int row = mi * 16 + (lane & 15);
            af2[mi] = *(const f16x8*)(T + ((row * 512 + kByte) ^ ((row & 7) << 4)));
        }
        #pragma unroll
        for (int di = 0; di < 8; ++di) {
            int d = wd + di * 16 + (lane & 15);
            bf2[di] = *(const f16x8*)((const char*)BmT + (size_t)d * 512 + kByte);
        }
        #pragma unroll
        for (int mi = 0; mi < 4; ++mi)
            #pragma unroll
            for (int di = 0; di < 8; ++di)
                acc2[mi][di] = __builtin_amdgcn_mfma_f32_16x16x32_f16(af2[mi], bf2[di], acc2[mi][di], 0, 0, 0);
    }

    size_t outBase = (size_t)b * (AW * BH);
    int w0 = wt * 64 + ((lane >> 4) << 2);
    int d0 = wd + (lane & 15);
    #pragma unroll
    for (int mi = 0; mi < 4; ++mi)
        #pragma unroll
        for (int di = 0; di < 8; ++di)
            #pragma unroll
            for (int r = 0; r < 4; ++r)
                out[outBase + (size_t)(w0 + mi * 16 + r) * BH + d0 + di * 16] = acc2[mi][di][r];
}

// ================= fallback path (round-7 proven): separate GEMM1 + GEMM2, xf16 in d_out ========
__global__ __launch_bounds__(256) void gemm1_kernel(
        const _Float16* __restrict__ Am, const _Float16* __restrict__ xf,
        _Float16* __restrict__ temp) {
    __shared__ __align__(16) char lds[32768];
    char* As = lds;
    char* Xs = lds + 16384;
    const int t = threadIdx.x;
    const int lane = t & 63;
    const int wave = t >> 6;
    const int wm = (wave >> 1) * 64;
    const int wn = (wave & 1) * 64;
    const int xcd = blockIdx.x & 7;
    const int seq = blockIdx.x >> 3;
    const int bx = xcd * 8 + (seq >> 3);
    const int by = seq & 7;
    const int sRow = t >> 3;
    const int sKk  = (t & 7) ^ (sRow & 7);
    const _Float16* aSrc = Am + ((size_t)by * 128 + sRow) * HW + sKk * 8;
    const _Float16* xSrc = xf + ((size_t)bx * 128 + sRow) * HW + sKk * 8;
    f32x4 acc[4][4] = {};
    for (int kt = 0; kt < HW; kt += 64) {
        __syncthreads();
        #pragma unroll
        for (int i = 0; i < 4; ++i)
            gload16(aSrc + kt + (size_t)i * 32 * HW, As + i * 4096 + t * 16);
        #pragma unroll
        for (int i = 0; i < 4; ++i)
            gload16(xSrc + kt + (size_t)i * 32 * HW, Xs + i * 4096 + t * 16);
        __syncthreads();
        #pragma unroll
        for (int k2 = 0; k2 < 2; ++k2) {
            f16x8 af[4], bf[4];
            int kByte = k2 * 64 + (lane >> 4) * 16;
            #pragma unroll
            for (int mi = 0; mi < 4; ++mi) {
                int row = wm + mi * 16 + (lane & 15);
                af[mi] = *(const f16x8*)(As + ((row * 128 + kByte) ^ ((row & 7) << 4)));
            }
            #pragma unroll
            for (int ni = 0; ni < 4; ++ni) {
                int row = wn + ni * 16 + (lane & 15);
                bf[ni] = *(const f16x8*)(Xs + ((row * 128 + kByte) ^ ((row & 7) << 4)));
            }
            #pragma unroll
            for (int mi = 0; mi < 4; ++mi)
                #pragma unroll
                for (int ni = 0; ni < 4; ++ni)
                    acc[mi][ni] = __builtin_amdgcn_mfma_f32_16x16x32_f16(af[mi], bf[ni], acc[mi][ni], 0, 0, 0);
        }
    }
    int row0 = by * 128 + wm + ((lane >> 4) << 2);
    int col0 = bx * 128 + wn + (lane & 15);
    #pragma unroll
    for (int mi = 0; mi < 4; ++mi)
        #pragma unroll
        for (int ni = 0; ni < 4; ++ni)
            #pragma unroll
            for (int r = 0; r < 4; ++r) {
                int gw = row0 + mi * 16 + r;
                int gc = col0 + ni * 16;
                int b = gc >> 8, c = gc & 255;
                temp[(size_t)b * (AW * CDIM) + (size_t)gw * CDIM + c] = (_Float16)acc[mi][ni][r];
            }
}

__global__ __launch_bounds__(256) void gemm2_kernel(
        const _Float16* __restrict__ A, long aStride,
        const _Float16* __restrict__ B,
        float* __restrict__ outP, int M, int N, int K) {
    __shared__ __align__(16) char lds[65536];
    const int t = threadIdx.x;
    const int lane = t & 63;
    const int wave = t >> 6;
    const int wm = (wave >> 1) * 64;
    const int wn = (wave & 1) * 64;
    const int z = blockIdx.z;
    const int r0 = t >> 3;
    const int kk = t & 7;
    const int kkSwz = kk ^ (r0 & 7);
    const _Float16* aSrc = A + (size_t)z * aStride + ((size_t)blockIdx.y * 128 + r0) * K + kkSwz * 8;
    const _Float16* bSrc = B + ((size_t)blockIdx.x * 128 + r0) * K + kkSwz * 8;
    f32x4 acc[4][4] = {};
    #define G2_STAGE(kt, asB, bsB)                                                 \
        _Pragma("unroll")                                                          \
        for (int i = 0; i < 4; ++i)                                                \
            gload16(aSrc + (kt) + (size_t)i * 32 * K, (asB) + i * 4096 + t * 16);  \
        _Pragma("unroll")                                                          \
        for (int i = 0; i < 4; ++i)                                                \
            gload16(bSrc + (kt) + (size_t)i * 32 * K, (bsB) + i * 4096 + t * 16);
    G2_STAGE(0, lds, lds + 16384)
    __syncthreads();
    const int NT = K / 64;
    for (int kt_i = 0; kt_i < NT; ++kt_i) {
        const int cur = kt_i & 1;
        char* AsC = lds + (cur ? 32768 : 0);
        char* BsC = AsC + 16384;
        char* AsN = lds + (cur ? 0 : 32768);
        char* BsN = AsN + 16384;
        if (kt_i == 0) { AsC = lds; BsC = lds + 16384; AsN = lds + 32768; BsN = lds + 49152; }
        if (kt_i + 1 < NT) { G2_STAGE((kt_i + 1) * 64, AsN, BsN) }
        #pragma unroll
        for (int k2 = 0; k2 < 2; ++k2) {
            f16x8 af[4], bf[4];
            int kByte = k2 * 64 + (lane >> 4) * 16;
            #pragma unroll
            for (int mi = 0; mi < 4; ++mi) {
                int row = wm + mi * 16 + (lane & 15);
                af[mi] = *(const f16x8*)(AsC + ((row * 128 + kByte) ^ ((row & 7) << 4)));
            }
            #pragma unroll
            for (int ni = 0; ni < 4; ++ni) {
                int row = wn + ni * 16 + (lane & 15);
                bf[ni] = *(const f16x8*)(BsC + ((row * 128 + kByte) ^ ((row & 7) << 4)));
            }
            #pragma unroll
            for (int mi = 0; mi < 4; ++mi)
                #pragma unroll
                for (int ni = 0; ni < 4; ++ni)
                    acc[mi][ni] = __builtin_amdgcn_mfma_f32_16x16x32_f16(af[mi], bf[ni], acc[mi][ni], 0, 0, 0);
        }
        __syncthreads();
    }
    int row0 = blockIdx.y * 128 + wm + ((lane >> 4) << 2);
    int col0 = blockIdx.x * 128 + wn + (lane & 15);
    size_t outBase = (size_t)z * M * N;
    #pragma unroll
    for (int mi = 0; mi < 4; ++mi)
        #pragma unroll
        for (int ni = 0; ni < 4; ++ni)
            #pragma unroll
            for (int r = 0; r < 4; ++r)
                outP[outBase + (size_t)(row0 + mi * 16 + r) * N + col0 + ni * 16] = acc[mi][ni][r];
}

// ---------------- launch ----------------
extern "C" void kernel_launch(void* const* d_in, const int* in_sizes, int n_in,
                              void* d_out, int out_size, void* d_ws, size_t ws_size,
                              hipStream_t stream) {
    const float* x     = (const float*)d_in[0];
    const float* A_ref = (const float*)d_in[1];
    const float* B_ref = (const float*)d_in[2];
    const float* sA    = (const float*)d_in[3];
    const float* sB    = (const float*)d_in[4];
    float* out = (float*)d_out;
    char* ws = (char*)d_ws;

    const int nA = AW * AH;  const unsigned jA = (unsigned)(nA / 2);
    const int nB = BW * BH;  const unsigned jB = (unsigned)(nB / 2);
    const int nx8 = (BATCH * CDIM * HW) / 8;
    const int outElems = BATCH * AW * BH;  // 16,777,216 f32

    // fused path needs: Am 8.39MB + BmT 0.26MB + xf16 67.1MB + scratch 0.2MB = ~76MB of ws
    const size_t FUSED_WS = 8388608ull + 262144ull + 67108864ull + SCRATCH_U32_TOTAL * 4ull;
    const bool fused = (ws_size >= FUSED_WS);

    _Float16* Am  = (_Float16*)(ws + 0);
    _Float16* BmT;
    _Float16* xf16;
    unsigned* scratch;
    _Float16* temp = nullptr;

    if (fused) {
        BmT     = (_Float16*)(ws + 8388608);
        xf16    = (_Float16*)(ws + 8650752);
        scratch = (unsigned*)(ws + 75759616);
    } else {
        BmT     = (_Float16*)(ws + 8388608);
        temp    = (_Float16*)(ws + 8650752);
        scratch = (unsigned*)(ws + 25427968);
        xf16    = (_Float16*)d_out;          // overlay; safe: gemm2 writes out after gemm1 reads xf
    }

    hipMemsetAsync(scratch, 0, MEMSET_U32 * 4, stream);

    // ---- mask pipeline + fused x conversion ----
    hist0_cvt_kernel<<<dim3(256, 4), 256, 0, stream>>>(sA, nA, sB, nB, x, xf16, nx8, scratch);
    hist1_kernel<<<dim3(256, 2), 256, 0, stream>>>(sA, nA, jA, sB, nB, jB, scratch);
    extract_kernel<<<dim3(256, 2), 256, 0, stream>>>(sA, nA, jA, sB, nB, jB, scratch);
    finalize_kernel<<<dim3(1, 2), 256, 0, stream>>>(scratch);
    apply_kernel<<<dim3(2048, 2), 256, 0, stream>>>(sA, A_ref, Am, out + outElems,
                                                    sB, B_ref, BmT, out + outElems + nA,
                                                    nA, nB, scratch);

    if (fused) {
        gemm_fused_kernel<<<512, 256, 0, stream>>>(Am, xf16, BmT, out);
    } else {
        gemm1_kernel<<<512, 256, 0, stream>>>(Am, xf16, temp);
        gemm2_kernel<<<dim3(BH / 128, AW / 128, BATCH), 256, 0, stream>>>(
            temp, (long)AW * CDIM, BmT, out, AW, BH, CDIM);
    }
}

// Round 9
// 195.229 us; speedup vs baseline: 1.0470x; 1.0470x over previous
//
#include <hip/hip_runtime.h>

typedef _Float16 f16x8 __attribute__((ext_vector_type(8)));
typedef _Float16 f16x4 __attribute__((ext_vector_type(4)));
typedef float    f32x4 __attribute__((ext_vector_type(4)));

static constexpr int BATCH = 32;
static constexpr int CDIM  = 256;    // C
static constexpr int HW    = 4096;   // h (= A_H = K of GEMM1)
static constexpr int AW    = 1024;   // A rows (w)
static constexpr int AH    = 4096;   // A cols (h)
static constexpr int BW    = 256;    // B rows (c)
static constexpr int BH    = 512;    // B cols (d)
static constexpr int CAND_CAP = 8192;

// scratch u32 layout (relative to scratch base)
// 0     histA0[4096]   4096  histA1[4096]
// 8192  histB0[4096]   12288 histB1[4096]
// 16384 selA[8]  ([3]=target2 [4]=vcut [5]=cutIdx [6]=candCount)
// 16392 selB[8]
// 16400 candBitsA[8192]  24592 candIdxA[8192]
// 32784 candBitsB[8192]  40976 candIdxB[8192]
static constexpr int MEMSET_U32 = 16400;

__device__ __forceinline__ void gload16(const void* g, void* l) {
    __builtin_amdgcn_global_load_lds((const __attribute__((address_space(1))) void*)g,
                                     (__attribute__((address_space(3))) void*)l, 16, 0, 0);
}

// every block computes the same select result from a global 4096-bin histogram.
__device__ void select_bin_inline(const unsigned* __restrict__ hist, unsigned target,
                                  unsigned* shp /*[256]*/, unsigned* res /*[2]*/) {
    const int t = threadIdx.x;
    unsigned sum = 0;
    #pragma unroll
    for (int k = 0; k < 16; ++k) sum += hist[t * 16 + k];
    shp[t] = sum;
    __syncthreads();
    if (t == 0) {
        unsigned c = 0; int k = 0;
        while (c + shp[k] <= target) { c += shp[k]; ++k; }
        int b = k * 16;
        while (true) { unsigned h = hist[b]; if (target < c + h) break; c += h; ++b; }
        res[0] = (unsigned)b; res[1] = c;
    }
    __syncthreads();
}

// ---------------- pass 0: hist of key>>19 (12 bits), per-wave LDS hist ----------------
__global__ void hist0_kernel(const float* __restrict__ sA, int nA,
                             const float* __restrict__ sB, int nB,
                             unsigned* __restrict__ scratch) {
    __shared__ unsigned lh[4][4096];
    const int y = blockIdx.y;
    const int t = threadIdx.x;
    const float* s = y ? sB : sA;
    const int n4 = (y ? nB : nA) >> 2;
    unsigned* hist = scratch + (y ? 8192 : 0);
    const int wave = t >> 6;
    for (int i = t; i < 4 * 4096; i += 256) ((unsigned*)lh)[i] = 0;
    __syncthreads();
    for (int i = blockIdx.x * 256 + t; i < n4; i += gridDim.x * 256) {
        float4 v = reinterpret_cast<const float4*>(s)[i];
        atomicAdd(&lh[wave][(__float_as_uint(v.x) & 0x7fffffffu) >> 19], 1u);
        atomicAdd(&lh[wave][(__float_as_uint(v.y) & 0x7fffffffu) >> 19], 1u);
        atomicAdd(&lh[wave][(__float_as_uint(v.z) & 0x7fffffffu) >> 19], 1u);
        atomicAdd(&lh[wave][(__float_as_uint(v.w) & 0x7fffffffu) >> 19], 1u);
    }
    __syncthreads();
    for (int b = t; b < 4096; b += 256) {
        unsigned v = lh[0][b] + lh[1][b] + lh[2][b] + lh[3][b];
        if (v) atomicAdd(&hist[b], v);
    }
}

// ---------------- pass 1: inline select0, hist of (key>>7)&4095 among prefix matches ----------------
__global__ void hist1_kernel(const float* __restrict__ sA, int nA, unsigned jA,
                             const float* __restrict__ sB, int nB, unsigned jB,
                             unsigned* __restrict__ scratch) {
    __shared__ unsigned lh[4][4096];
    __shared__ unsigned shp[256];
    __shared__ unsigned res[2];
    const int y = blockIdx.y;
    const float* s = y ? sB : sA;
    const int n4 = (y ? nB : nA) >> 2;
    const unsigned j = y ? jB : jA;
    const unsigned* hist0 = scratch + (y ? 8192 : 0);
    unsigned* hist1 = scratch + 4096 + (y ? 8192 : 0);
    const int t = threadIdx.x;
    const int wave = t >> 6;
    for (int i = t; i < 4 * 4096; i += 256) ((unsigned*)lh)[i] = 0;
    select_bin_inline(hist0, j, shp, res);       // includes syncthreads
    const unsigned bin0 = res[0];
    for (int i = blockIdx.x * 256 + t; i < n4; i += gridDim.x * 256) {
        float4 v = reinterpret_cast<const float4*>(s)[i];
        unsigned k0 = __float_as_uint(v.x) & 0x7fffffffu;
        unsigned k1 = __float_as_uint(v.y) & 0x7fffffffu;
        unsigned k2 = __float_as_uint(v.z) & 0x7fffffffu;
        unsigned k3 = __float_as_uint(v.w) & 0x7fffffffu;
        if ((k0 >> 19) == bin0) atomicAdd(&lh[wave][(k0 >> 7) & 4095], 1u);
        if ((k1 >> 19) == bin0) atomicAdd(&lh[wave][(k1 >> 7) & 4095], 1u);
        if ((k2 >> 19) == bin0) atomicAdd(&lh[wave][(k2 >> 7) & 4095], 1u);
        if ((k3 >> 19) == bin0) atomicAdd(&lh[wave][(k3 >> 7) & 4095], 1u);
    }
    __syncthreads();
    for (int b = t; b < 4096; b += 256) {
        unsigned v = lh[0][b] + lh[1][b] + lh[2][b] + lh[3][b];
        if (v) atomicAdd(&hist1[b], v);
    }
}

// ---------------- extract: inline select0+select1, gather candidates with 24-bit prefix ----------------
__global__ void extract_kernel(const float* __restrict__ sA, int nA, unsigned jA,
                               const float* __restrict__ sB, int nB, unsigned jB,
                               unsigned* __restrict__ scratch) {
    __shared__ unsigned shp[256];
    __shared__ unsigned res0[2], res1[2];
    const int y = blockIdx.y;
    const float* s = y ? sB : sA;
    const int n4 = (y ? nB : nA) >> 2;
    const unsigned j = y ? jB : jA;
    const unsigned* hist0 = scratch + (y ? 8192 : 0);
    const unsigned* hist1 = scratch + 4096 + (y ? 8192 : 0);
    unsigned* sel = scratch + 16384 + y * 8;
    unsigned* candBits = scratch + (y ? 32784 : 16400);
    unsigned* candIdx  = candBits + CAND_CAP;
    const int t = threadIdx.x;
    select_bin_inline(hist0, j, shp, res0);
    select_bin_inline(hist1, j - res0[1], shp, res1);
    const unsigned pref = (res0[0] << 12) | res1[0];
    const unsigned base2 = res0[1] + res1[1];
    if (blockIdx.x == 0 && t == 0) sel[3] = j - base2;   // rank within candidate set
    for (int i = blockIdx.x * 256 + t; i < n4; i += gridDim.x * 256) {
        float4 v = reinterpret_cast<const float4*>(s)[i];
        #pragma unroll
        for (int k = 0; k < 4; ++k) {
            unsigned bits = __float_as_uint(k == 0 ? v.x : k == 1 ? v.y : k == 2 ? v.z : v.w) & 0x7fffffffu;
            if ((bits >> 7) == pref) {
                unsigned p = atomicAdd(&sel[6], 1u);
                if (p < CAND_CAP) { candBits[p] = bits; candIdx[p] = (unsigned)(i * 4 + k); }
            }
        }
    }
}

// ---------------- finalize: exact (value, index)-lexicographic rank among candidates ----------------
__global__ void finalize_kernel(unsigned* __restrict__ scratch) {
    __shared__ unsigned sb[CAND_CAP];
    __shared__ unsigned si[CAND_CAP];
    const int y = blockIdx.y;
    unsigned* sel = scratch + 16384 + y * 8;
    const unsigned* candBits = scratch + (y ? 32784 : 16400);
    const unsigned* candIdx  = candBits + CAND_CAP;
    const int t = threadIdx.x;
    unsigned cnt = sel[6]; if (cnt > CAND_CAP) cnt = CAND_CAP;
    const unsigned target = sel[3];
    for (unsigned c = t; c < cnt; c += 256) { sb[c] = candBits[c]; si[c] = candIdx[c]; }
    __syncthreads();
    for (unsigned c = t; c < cnt; c += 256) {
        unsigned b = sb[c], ix = si[c];
        unsigned r = 0;
        for (unsigned q = 0; q < cnt; ++q)
            r += (sb[q] < b) || (sb[q] == b && si[q] < ix);
        if (r == target) { sel[4] = b; sel[5] = ix; }
    }
}

// -------- apply + cvt: y=0 A-mask, y=1 B-mask, y=2..5 x f32->f16 slabs (rides last pre-GEMM) -----
__global__ void apply_cvt_kernel(const float* __restrict__ sA, const float* __restrict__ wA,
                                 _Float16* __restrict__ Am, float* __restrict__ wcopyA,
                                 const float* __restrict__ sB, const float* __restrict__ wB,
                                 _Float16* __restrict__ BmT, float* __restrict__ wcopyB,
                                 int nA, int nB,
                                 const float* __restrict__ x, _Float16* __restrict__ xf, int nx8,
                                 const unsigned* __restrict__ scratch) {
    const int y = blockIdx.y;
    const int t = threadIdx.x;
    if (y >= 2) {
        // x conversion: 4 parallel slabs
        int vb = (y - 2) * gridDim.x + blockIdx.x;
        int stride = 4 * gridDim.x * 256;
        for (int i = vb * 256 + t; i < nx8; i += stride) {
            f32x4 v0 = reinterpret_cast<const f32x4*>(x)[i * 2];
            f32x4 v1 = reinterpret_cast<const f32x4*>(x)[i * 2 + 1];
            f16x8 h = { (_Float16)v0[0], (_Float16)v0[1], (_Float16)v0[2], (_Float16)v0[3],
                        (_Float16)v1[0], (_Float16)v1[1], (_Float16)v1[2], (_Float16)v1[3] };
            reinterpret_cast<f16x8*>(xf)[i] = h;
        }
        return;
    }
    const float* s = y ? sB : sA;
    const float* w = y ? wB : wA;
    float* wcopy = y ? wcopyB : wcopyA;
    const int n4 = (y ? nB : nA) >> 2;
    const unsigned* sel = scratch + 16384 + y * 8;
    const unsigned vcut = sel[4], cutIdx = sel[5];
    for (int i = blockIdx.x * 256 + t; i < n4; i += gridDim.x * 256) {
        float4 sv = reinterpret_cast<const float4*>(s)[i];
        float4 wv = reinterpret_cast<const float4*>(w)[i];
        reinterpret_cast<float4*>(wcopy)[i] = wv;
        unsigned idx0 = (unsigned)i * 4;
        float m[4];
        #pragma unroll
        for (int k = 0; k < 4; ++k) {
            unsigned bits = __float_as_uint(k == 0 ? sv.x : k == 1 ? sv.y : k == 2 ? sv.z : sv.w) & 0x7fffffffu;
            bool keep = (bits > vcut) || (bits == vcut && (idx0 + k) >= cutIdx);
            m[k] = keep ? 1.0f : 0.0f;
        }
        if (!y) {
            f16x4 o = { (_Float16)(wv.x * m[0]), (_Float16)(wv.y * m[1]),
                        (_Float16)(wv.z * m[2]), (_Float16)(wv.w * m[3]) };
            *reinterpret_cast<f16x4*>(Am + idx0) = o;
        } else {
            int c = (int)(idx0 >> 9);           // row of B_ref [256][512]
            int d = (int)(idx0 & 511);
            BmT[(size_t)(d + 0) * BW + c] = (_Float16)(wv.x * m[0]);
            BmT[(size_t)(d + 1) * BW + c] = (_Float16)(wv.y * m[1]);
            BmT[(size_t)(d + 2) * BW + c] = (_Float16)(wv.z * m[2]);
            BmT[(size_t)(d + 3) * BW + c] = (_Float16)(wv.w * m[3]);
        }
    }
}

// ---------------- GEMM1 (m97-exact, proven 77.5us): temp[b][w][c] = sum_h Am[w][h]*xf[(b,c)][h] --
// Both operands f16 via global_load_lds (pre-swizzled source, linear LDS dest), single 32KB buffer,
// 2-barrier K-loop. 128x128 tile, 4 waves (2x2), 4x4 mfma_f32_16x16x32_f16 per wave.
// XCD-local x reuse: XCD k owns bx in [8k,8k+8); all 8 by per bx run on that XCD.
__global__ __launch_bounds__(256) void gemm1_kernel(
        const _Float16* __restrict__ Am, const _Float16* __restrict__ xf,
        _Float16* __restrict__ temp) {
    __shared__ __align__(16) char lds[32768];
    char* As = lds;
    char* Xs = lds + 16384;
    const int t = threadIdx.x;
    const int lane = t & 63;
    const int wave = t >> 6;
    const int wm = (wave >> 1) * 64;
    const int wn = (wave & 1) * 64;
    const int xcd = blockIdx.x & 7;
    const int seq = blockIdx.x >> 3;
    const int bx = xcd * 8 + (seq >> 3);
    const int by = seq & 7;
    const int sRow = t >> 3;
    const int sKk  = (t & 7) ^ (sRow & 7);
    const _Float16* aSrc = Am + ((size_t)by * 128 + sRow) * HW + sKk * 8;
    const _Float16* xSrc = xf + ((size_t)bx * 128 + sRow) * HW + sKk * 8;
    f32x4 acc[4][4] = {};
    for (int kt = 0; kt < HW; kt += 64) {
        __syncthreads();
        #pragma unroll
        for (int i = 0; i < 4; ++i)
            gload16(aSrc + kt + (size_t)i * 32 * HW, As + i * 4096 + t * 16);
        #pragma unroll
        for (int i = 0; i < 4; ++i)
            gload16(xSrc + kt + (size_t)i * 32 * HW, Xs + i * 4096 + t * 16);
        __syncthreads();
        #pragma unroll
        for (int k2 = 0; k2 < 2; ++k2) {
            f16x8 af[4], bf[4];
            int kByte = k2 * 64 + (lane >> 4) * 16;
            #pragma unroll
            for (int mi = 0; mi < 4; ++mi) {
                int row = wm + mi * 16 + (lane & 15);
                af[mi] = *(const f16x8*)(As + ((row * 128 + kByte) ^ ((row & 7) << 4)));
            }
            #pragma unroll
            for (int ni = 0; ni < 4; ++ni) {
                int row = wn + ni * 16 + (lane & 15);
                bf[ni] = *(const f16x8*)(Xs + ((row * 128 + kByte) ^ ((row & 7) << 4)));
            }
            #pragma unroll
            for (int mi = 0; mi < 4; ++mi)
                #pragma unroll
                for (int ni = 0; ni < 4; ++ni)
                    acc[mi][ni] = __builtin_amdgcn_mfma_f32_16x16x32_f16(af[mi], bf[ni], acc[mi][ni], 0, 0, 0);
        }
    }
    int row0 = by * 128 + wm + ((lane >> 4) << 2);
    int col0 = bx * 128 + wn + (lane & 15);
    #pragma unroll
    for (int mi = 0; mi < 4; ++mi)
        #pragma unroll
        for (int ni = 0; ni < 4; ++ni)
            #pragma unroll
            for (int r = 0; r < 4; ++r) {
                int gw = row0 + mi * 16 + r;
                int gc = col0 + ni * 16;
                int b = gc >> 8, c = gc & 255;
                temp[(size_t)b * (AW * CDIM) + (size_t)gw * CDIM + c] = (_Float16)acc[mi][ni][r];
            }
}

// ---------------- GEMM2 (single-buffer, TLP-hidden; K=256): out[b][w][d] = sum_c temp*BmT --------
// 32KB LDS -> 4-5 blocks/CU; short K makes dbuf prologue overhead not worth it (m114: TLP overlap).
__global__ __launch_bounds__(256) void gemm2_kernel(
        const _Float16* __restrict__ A, long aStride,
        const _Float16* __restrict__ B,
        float* __restrict__ outP, int M, int N, int K) {
    __shared__ __align__(16) char lds[32768];
    char* As = lds;
    char* Bs = lds + 16384;
    const int t = threadIdx.x;
    const int lane = t & 63;
    const int wave = t >> 6;
    const int wm = (wave >> 1) * 64;
    const int wn = (wave & 1) * 64;
    const int z = blockIdx.z;
    const int r0 = t >> 3;
    const int kk = t & 7;
    const int kkSwz = kk ^ (r0 & 7);
    const _Float16* aSrc = A + (size_t)z * aStride + ((size_t)blockIdx.y * 128 + r0) * K + kkSwz * 8;
    const _Float16* bSrc = B + ((size_t)blockIdx.x * 128 + r0) * K + kkSwz * 8;
    f32x4 acc[4][4] = {};
    for (int kt = 0; kt < K; kt += 64) {
        __syncthreads();
        #pragma unroll
        for (int i = 0; i < 4; ++i)
            gload16(aSrc + kt + (size_t)i * 32 * K, As + i * 4096 + t * 16);
        #pragma unroll
        for (int i = 0; i < 4; ++i)
            gload16(bSrc + kt + (size_t)i * 32 * K, Bs + i * 4096 + t * 16);
        __syncthreads();
        #pragma unroll
        for (int k2 = 0; k2 < 2; ++k2) {
            f16x8 af[4], bf[4];
            int kByte = k2 * 64 + (lane >> 4) * 16;
            #pragma unroll
            for (int mi = 0; mi < 4; ++mi) {
                int row = wm + mi * 16 + (lane & 15);
                af[mi] = *(const f16x8*)(As + ((row * 128 + kByte) ^ ((row & 7) << 4)));
            }
            #pragma unroll
            for (int ni = 0; ni < 4; ++ni) {
                int row = wn + ni * 16 + (lane & 15);
                bf[ni] = *(const f16x8*)(Bs + ((row * 128 + kByte) ^ ((row & 7) << 4)));
            }
            #pragma unroll
            for (int mi = 0; mi < 4; ++mi)
                #pragma unroll
                for (int ni = 0; ni < 4; ++ni)
                    acc[mi][ni] = __builtin_amdgcn_mfma_f32_16x16x32_f16(af[mi], bf[ni], acc[mi][ni], 0, 0, 0);
        }
    }
    int row0 = blockIdx.y * 128 + wm + ((lane >> 4) << 2);
    int col0 = blockIdx.x * 128 + wn + (lane & 15);
    size_t outBase = (size_t)z * M * N;
    #pragma unroll
    for (int mi = 0; mi < 4; ++mi)
        #pragma unroll
        for (int ni = 0; ni < 4; ++ni)
            #pragma unroll
            for (int r = 0; r < 4; ++r)
                outP[outBase + (size_t)(row0 + mi * 16 + r) * N + col0 + ni * 16] = acc[mi][ni][r];
}

// ---------------- launch ----------------
extern "C" void kernel_launch(void* const* d_in, const int* in_sizes, int n_in,
                              void* d_out, int out_size, void* d_ws, size_t ws_size,
                              hipStream_t stream) {
    const float* x     = (const float*)d_in[0];
    const float* A_ref = (const float*)d_in[1];
    const float* B_ref = (const float*)d_in[2];
    const float* sA    = (const float*)d_in[3];
    const float* sB    = (const float*)d_in[4];
    float* out = (float*)d_out;
    char* ws = (char*)d_ws;

    const int nA = AW * AH;  const unsigned jA = (unsigned)(nA / 2);
    const int nB = BW * BH;  const unsigned jB = (unsigned)(nB / 2);
    const int nx8 = (BATCH * CDIM * HW) / 8;
    const int outElems = BATCH * AW * BH;  // 16,777,216 f32 (= 67.1MB, exactly xf16's size)

    _Float16* Am     = (_Float16*)(ws + 0);          // [1024][4096] f16
    _Float16* BmT    = (_Float16*)(ws + 8388608);    // [512][256]  f16
    _Float16* temp   = (_Float16*)(ws + 8650752);    // [32][1024][256] f16
    unsigned* scratch= (unsigned*)(ws + 25427968);

    // x (f16) overlays the d_out "out" region; gemm2 overwrites it only after gemm1 consumed it
    _Float16* xf16 = (_Float16*)d_out;

    hipMemsetAsync(scratch, 0, MEMSET_U32 * 4, stream);

    // ---- mask pipeline; x cvt deferred to the LAST pre-GEMM dispatch (keeps chain short) ----
    hist0_kernel<<<dim3(256, 2), 256, 0, stream>>>(sA, nA, sB, nB, scratch);
    hist1_kernel<<<dim3(256, 2), 256, 0, stream>>>(sA, nA, jA, sB, nB, jB, scratch);
    extract_kernel<<<dim3(256, 2), 256, 0, stream>>>(sA, nA, jA, sB, nB, jB, scratch);
    finalize_kernel<<<dim3(1, 2), 256, 0, stream>>>(scratch);
    apply_cvt_kernel<<<dim3(1024, 6), 256, 0, stream>>>(sA, A_ref, Am, out + outElems,
                                                        sB, B_ref, BmT, out + outElems + nA,
                                                        nA, nB, x, xf16, nx8, scratch);

    // ---- GEMM1 (m97-exact, both operands f16 gload_lds, XCD-local x reuse) ----
    gemm1_kernel<<<512, 256, 0, stream>>>(Am, xf16, temp);

    // ---- GEMM2 (single-buffer, 4-5 blocks/CU) ----
    gemm2_kernel<<<dim3(BH / 128, AW / 128, BATCH), 256, 0, stream>>>(
        temp, (long)AW * CDIM, BmT, out, AW, BH, CDIM);
}

// Round 10
// 187.633 us; speedup vs baseline: 1.0894x; 1.0405x over previous
//
#include <hip/hip_runtime.h>

typedef _Float16 f16x8 __attribute__((ext_vector_type(8)));
typedef _Float16 f16x4 __attribute__((ext_vector_type(4)));
typedef float    f32x4 __attribute__((ext_vector_type(4)));

static constexpr int BATCH = 32;
static constexpr int CDIM  = 256;    // C
static constexpr int HW    = 4096;   // h (= A_H = K of GEMM1)
static constexpr int AW    = 1024;   // A rows (w)
static constexpr int AH    = 4096;   // A cols (h)
static constexpr int BW    = 256;    // B rows (c)
static constexpr int BH    = 512;    // B cols (d)
static constexpr int CAND_CAP = 8192;

// scratch u32 layout (relative to scratch base)
// 0     histA0[4096]   4096  histA1[4096]
// 8192  histB0[4096]   12288 histB1[4096]
// 16384 selA[8]  ([3]=target2 [6]=candCount)   16392 selB[8]
// 16400 candBitsA[8192]  24592 candIdxA[8192]
// 32784 candBitsB[8192]  40976 candIdxB[8192]
static constexpr int MEMSET_U32 = 16400;

__device__ __forceinline__ void gload16(const void* g, void* l) {
    __builtin_amdgcn_global_load_lds((const __attribute__((address_space(1))) void*)g,
                                     (__attribute__((address_space(3))) void*)l, 16, 0, 0);
}

// every block computes the same select result from a global 4096-bin histogram.
__device__ void select_bin_inline(const unsigned* __restrict__ hist, unsigned target,
                                  unsigned* shp /*[256]*/, unsigned* res /*[2]*/) {
    const int t = threadIdx.x;
    unsigned sum = 0;
    #pragma unroll
    for (int k = 0; k < 16; ++k) sum += hist[t * 16 + k];
    shp[t] = sum;
    __syncthreads();
    if (t == 0) {
        unsigned c = 0; int k = 0;
        while (c + shp[k] <= target) { c += shp[k]; ++k; }
        int b = k * 16;
        while (true) { unsigned h = hist[b]; if (target < c + h) break; c += h; ++b; }
        res[0] = (unsigned)b; res[1] = c;
    }
    __syncthreads();
}

// ---------------- pass 0: hist of key>>19 (12 bits), per-wave LDS hist ----------------
__global__ void hist0_kernel(const float* __restrict__ sA, int nA,
                             const float* __restrict__ sB, int nB,
                             unsigned* __restrict__ scratch) {
    __shared__ unsigned lh[4][4096];
    const int y = blockIdx.y;
    const int t = threadIdx.x;
    const float* s = y ? sB : sA;
    const int n4 = (y ? nB : nA) >> 2;
    unsigned* hist = scratch + (y ? 8192 : 0);
    const int wave = t >> 6;
    for (int i = t; i < 4 * 4096; i += 256) ((unsigned*)lh)[i] = 0;
    __syncthreads();
    for (int i = blockIdx.x * 256 + t; i < n4; i += gridDim.x * 256) {
        float4 v = reinterpret_cast<const float4*>(s)[i];
        atomicAdd(&lh[wave][(__float_as_uint(v.x) & 0x7fffffffu) >> 19], 1u);
        atomicAdd(&lh[wave][(__float_as_uint(v.y) & 0x7fffffffu) >> 19], 1u);
        atomicAdd(&lh[wave][(__float_as_uint(v.z) & 0x7fffffffu) >> 19], 1u);
        atomicAdd(&lh[wave][(__float_as_uint(v.w) & 0x7fffffffu) >> 19], 1u);
    }
    __syncthreads();
    for (int b = t; b < 4096; b += 256) {
        unsigned v = lh[0][b] + lh[1][b] + lh[2][b] + lh[3][b];
        if (v) atomicAdd(&hist[b], v);
    }
}

// ---------------- pass 1: inline select0, hist of (key>>7)&4095 among prefix matches ----------------
__global__ void hist1_kernel(const float* __restrict__ sA, int nA, unsigned jA,
                             const float* __restrict__ sB, int nB, unsigned jB,
                             unsigned* __restrict__ scratch) {
    __shared__ unsigned lh[4][4096];
    __shared__ unsigned shp[256];
    __shared__ unsigned res[2];
    const int y = blockIdx.y;
    const float* s = y ? sB : sA;
    const int n4 = (y ? nB : nA) >> 2;
    const unsigned j = y ? jB : jA;
    const unsigned* hist0 = scratch + (y ? 8192 : 0);
    unsigned* hist1 = scratch + 4096 + (y ? 8192 : 0);
    const int t = threadIdx.x;
    const int wave = t >> 6;
    for (int i = t; i < 4 * 4096; i += 256) ((unsigned*)lh)[i] = 0;
    select_bin_inline(hist0, j, shp, res);       // includes syncthreads
    const unsigned bin0 = res[0];
    for (int i = blockIdx.x * 256 + t; i < n4; i += gridDim.x * 256) {
        float4 v = reinterpret_cast<const float4*>(s)[i];
        unsigned k0 = __float_as_uint(v.x) & 0x7fffffffu;
        unsigned k1 = __float_as_uint(v.y) & 0x7fffffffu;
        unsigned k2 = __float_as_uint(v.z) & 0x7fffffffu;
        unsigned k3 = __float_as_uint(v.w) & 0x7fffffffu;
        if ((k0 >> 19) == bin0) atomicAdd(&lh[wave][(k0 >> 7) & 4095], 1u);
        if ((k1 >> 19) == bin0) atomicAdd(&lh[wave][(k1 >> 7) & 4095], 1u);
        if ((k2 >> 19) == bin0) atomicAdd(&lh[wave][(k2 >> 7) & 4095], 1u);
        if ((k3 >> 19) == bin0) atomicAdd(&lh[wave][(k3 >> 7) & 4095], 1u);
    }
    __syncthreads();
    for (int b = t; b < 4096; b += 256) {
        unsigned v = lh[0][b] + lh[1][b] + lh[2][b] + lh[3][b];
        if (v) atomicAdd(&hist1[b], v);
    }
}

// ---------------- extract: inline select0+select1, gather candidates with 24-bit prefix ----------------
__global__ void extract_kernel(const float* __restrict__ sA, int nA, unsigned jA,
                               const float* __restrict__ sB, int nB, unsigned jB,
                               unsigned* __restrict__ scratch) {
    __shared__ unsigned shp[256];
    __shared__ unsigned res0[2], res1[2];
    const int y = blockIdx.y;
    const float* s = y ? sB : sA;
    const int n4 = (y ? nB : nA) >> 2;
    const unsigned j = y ? jB : jA;
    const unsigned* hist0 = scratch + (y ? 8192 : 0);
    const unsigned* hist1 = scratch + 4096 + (y ? 8192 : 0);
    unsigned* sel = scratch + 16384 + y * 8;
    unsigned* candBits = scratch + (y ? 32784 : 16400);
    unsigned* candIdx  = candBits + CAND_CAP;
    const int t = threadIdx.x;
    select_bin_inline(hist0, j, shp, res0);
    select_bin_inline(hist1, j - res0[1], shp, res1);
    const unsigned pref = (res0[0] << 12) | res1[0];
    const unsigned base2 = res0[1] + res1[1];
    if (blockIdx.x == 0 && t == 0) sel[3] = j - base2;   // rank within candidate set
    for (int i = blockIdx.x * 256 + t; i < n4; i += gridDim.x * 256) {
        float4 v = reinterpret_cast<const float4*>(s)[i];
        #pragma unroll
        for (int k = 0; k < 4; ++k) {
            unsigned bits = __float_as_uint(k == 0 ? v.x : k == 1 ? v.y : k == 2 ? v.z : v.w) & 0x7fffffffu;
            if ((bits >> 7) == pref) {
                unsigned p = atomicAdd(&sel[6], 1u);
                if (p < CAND_CAP) { candBits[p] = bits; candIdx[p] = (unsigned)(i * 4 + k); }
            }
        }
    }
}

// -------- apply + cvt (+ inline finalize): y=0 A-mask, y=1 B-mask, y=2..5 x f32->f16 slabs -------
// finalize is recomputed per mask block: exact (value,index)-lex rank over the ~27 candidates that
// share the 24-bit prefix (O(cnt^2/256) per thread; cnt is typically ~27, capped at CAND_CAP).
__global__ void apply_cvt_kernel(const float* __restrict__ sA, const float* __restrict__ wA,
                                 _Float16* __restrict__ Am, float* __restrict__ wcopyA,
                                 const float* __restrict__ sB, const float* __restrict__ wB,
                                 _Float16* __restrict__ BmT, float* __restrict__ wcopyB,
                                 int nA, int nB,
                                 const float* __restrict__ x, _Float16* __restrict__ xf, int nx8,
                                 const unsigned* __restrict__ scratch) {
    const int y = blockIdx.y;
    const int t = threadIdx.x;
    if (y >= 2) {
        // x conversion: 4 parallel slabs
        int vb = (y - 2) * gridDim.x + blockIdx.x;
        int stride = 4 * gridDim.x * 256;
        for (int i = vb * 256 + t; i < nx8; i += stride) {
            f32x4 v0 = reinterpret_cast<const f32x4*>(x)[i * 2];
            f32x4 v1 = reinterpret_cast<const f32x4*>(x)[i * 2 + 1];
            f16x8 h = { (_Float16)v0[0], (_Float16)v0[1], (_Float16)v0[2], (_Float16)v0[3],
                        (_Float16)v1[0], (_Float16)v1[1], (_Float16)v1[2], (_Float16)v1[3] };
            reinterpret_cast<f16x8*>(xf)[i] = h;
        }
        return;
    }
    // ---- inline finalize ----
    __shared__ unsigned s_vcut, s_cut;
    const unsigned* sel = scratch + 16384 + y * 8;
    const unsigned* candBits = scratch + (y ? 32784 : 16400);
    const unsigned* candIdx  = candBits + CAND_CAP;
    if (t == 0) { s_vcut = 0u; s_cut = 0u; }
    __syncthreads();
    {
        unsigned cnt = sel[6]; if (cnt > CAND_CAP) cnt = CAND_CAP;
        const unsigned target = sel[3];
        for (unsigned c = t; c < cnt; c += 256) {
            unsigned b = candBits[c], ix = candIdx[c];
            unsigned r = 0;
            for (unsigned q = 0; q < cnt; ++q) {
                unsigned bq = candBits[q];
                r += (bq < b) || (bq == b && candIdx[q] < ix);
            }
            if (r == target) { s_vcut = b; s_cut = ix; }
        }
    }
    __syncthreads();
    const unsigned vcut = s_vcut, cutIdx = s_cut;

    const float* s = y ? sB : sA;
    const float* w = y ? wB : wA;
    float* wcopy = y ? wcopyB : wcopyA;
    const int n4 = (y ? nB : nA) >> 2;
    for (int i = blockIdx.x * 256 + t; i < n4; i += gridDim.x * 256) {
        float4 sv = reinterpret_cast<const float4*>(s)[i];
        float4 wv = reinterpret_cast<const float4*>(w)[i];
        reinterpret_cast<float4*>(wcopy)[i] = wv;
        unsigned idx0 = (unsigned)i * 4;
        float m[4];
        #pragma unroll
        for (int k = 0; k < 4; ++k) {
            unsigned bits = __float_as_uint(k == 0 ? sv.x : k == 1 ? sv.y : k == 2 ? sv.z : sv.w) & 0x7fffffffu;
            bool keep = (bits > vcut) || (bits == vcut && (idx0 + k) >= cutIdx);
            m[k] = keep ? 1.0f : 0.0f;
        }
        if (!y) {
            f16x4 o = { (_Float16)(wv.x * m[0]), (_Float16)(wv.y * m[1]),
                        (_Float16)(wv.z * m[2]), (_Float16)(wv.w * m[3]) };
            *reinterpret_cast<f16x4*>(Am + idx0) = o;
        } else {
            int c = (int)(idx0 >> 9);           // row of B_ref [256][512]
            int d = (int)(idx0 & 511);
            BmT[(size_t)(d + 0) * BW + c] = (_Float16)(wv.x * m[0]);
            BmT[(size_t)(d + 1) * BW + c] = (_Float16)(wv.y * m[1]);
            BmT[(size_t)(d + 2) * BW + c] = (_Float16)(wv.z * m[2]);
            BmT[(size_t)(d + 3) * BW + c] = (_Float16)(wv.w * m[3]);
        }
    }
}

// ---------------- GEMM1 (m97-exact, proven 79.5us): temp[b][w][c] = sum_h Am[w][h]*xf[(b,c)][h] --
// Both operands f16 via global_load_lds (pre-swizzled source, linear LDS dest), single 32KB buffer,
// 2-barrier K-loop. 128x128 tile, 4 waves (2x2), 4x4 mfma_f32_16x16x32_f16 per wave.
// XCD-local x reuse: XCD k owns bx in [8k,8k+8); all 8 by per bx run on that XCD.
__global__ __launch_bounds__(256) void gemm1_kernel(
        const _Float16* __restrict__ Am, const _Float16* __restrict__ xf,
        _Float16* __restrict__ temp) {
    __shared__ __align__(16) char lds[32768];
    char* As = lds;
    char* Xs = lds + 16384;
    const int t = threadIdx.x;
    const int lane = t & 63;
    const int wave = t >> 6;
    const int wm = (wave >> 1) * 64;
    const int wn = (wave & 1) * 64;
    const int xcd = blockIdx.x & 7;
    const int seq = blockIdx.x >> 3;
    const int bx = xcd * 8 + (seq >> 3);
    const int by = seq & 7;
    const int sRow = t >> 3;
    const int sKk  = (t & 7) ^ (sRow & 7);
    const _Float16* aSrc = Am + ((size_t)by * 128 + sRow) * HW + sKk * 8;
    const _Float16* xSrc = xf + ((size_t)bx * 128 + sRow) * HW + sKk * 8;
    f32x4 acc[4][4] = {};
    for (int kt = 0; kt < HW; kt += 64) {
        __syncthreads();
        #pragma unroll
        for (int i = 0; i < 4; ++i)
            gload16(aSrc + kt + (size_t)i * 32 * HW, As + i * 4096 + t * 16);
        #pragma unroll
        for (int i = 0; i < 4; ++i)
            gload16(xSrc + kt + (size_t)i * 32 * HW, Xs + i * 4096 + t * 16);
        __syncthreads();
        #pragma unroll
        for (int k2 = 0; k2 < 2; ++k2) {
            f16x8 af[4], bf[4];
            int kByte = k2 * 64 + (lane >> 4) * 16;
            #pragma unroll
            for (int mi = 0; mi < 4; ++mi) {
                int row = wm + mi * 16 + (lane & 15);
                af[mi] = *(const f16x8*)(As + ((row * 128 + kByte) ^ ((row & 7) << 4)));
            }
            #pragma unroll
            for (int ni = 0; ni < 4; ++ni) {
                int row = wn + ni * 16 + (lane & 15);
                bf[ni] = *(const f16x8*)(Xs + ((row * 128 + kByte) ^ ((row & 7) << 4)));
            }
            #pragma unroll
            for (int mi = 0; mi < 4; ++mi)
                #pragma unroll
                for (int ni = 0; ni < 4; ++ni)
                    acc[mi][ni] = __builtin_amdgcn_mfma_f32_16x16x32_f16(af[mi], bf[ni], acc[mi][ni], 0, 0, 0);
        }
    }
    int row0 = by * 128 + wm + ((lane >> 4) << 2);
    int col0 = bx * 128 + wn + (lane & 15);
    #pragma unroll
    for (int mi = 0; mi < 4; ++mi)
        #pragma unroll
        for (int ni = 0; ni < 4; ++ni)
            #pragma unroll
            for (int r = 0; r < 4; ++r) {
                int gw = row0 + mi * 16 + r;
                int gc = col0 + ni * 16;
                int b = gc >> 8, c = gc & 255;
                temp[(size_t)b * (AW * CDIM) + (size_t)gw * CDIM + c] = (_Float16)acc[mi][ni][r];
            }
}

// ---------------- GEMM2 (single-buffer, XCD-grouped): out[b][w][d] = sum_c temp*BmT --------------
// Flat 1024-block grid; XCD k owns linear ids [128k, 128k+128): bx fastest -> the 4 blocks sharing
// a temp A-tile run consecutively on ONE XCD -> temp fetched once per tile (L2 hit for the rest).
__global__ __launch_bounds__(256) void gemm2_kernel(
        const _Float16* __restrict__ A,    // temp [32][1024][256]
        const _Float16* __restrict__ B,    // BmT  [512][256]
        float* __restrict__ outP) {        // out  [32][1024][512]
    __shared__ __align__(16) char lds[32768];
    char* As = lds;
    char* Bs = lds + 16384;
    const int t = threadIdx.x;
    const int lane = t & 63;
    const int wave = t >> 6;
    const int wm = (wave >> 1) * 64;
    const int wn = (wave & 1) * 64;
    constexpr int K = CDIM;            // 256

    const int l  = (blockIdx.x & 7) * 128 + (blockIdx.x >> 3);
    const int bx = l & 3;              // d-tile 0..3
    const int by = (l >> 2) & 7;       // w-tile 0..7
    const int z  = l >> 5;             // batch 0..31

    const int r0 = t >> 3;
    const int kk = t & 7;
    const int kkSwz = kk ^ (r0 & 7);
    const _Float16* aSrc = A + (size_t)z * (AW * CDIM) + ((size_t)by * 128 + r0) * K + kkSwz * 8;
    const _Float16* bSrc = B + ((size_t)bx * 128 + r0) * K + kkSwz * 8;
    f32x4 acc[4][4] = {};
    for (int kt = 0; kt < K; kt += 64) {
        __syncthreads();
        #pragma unroll
        for (int i = 0; i < 4; ++i)
            gload16(aSrc + kt + (size_t)i * 32 * K, As + i * 4096 + t * 16);
        #pragma unroll
        for (int i = 0; i < 4; ++i)
            gload16(bSrc + kt + (size_t)i * 32 * K, Bs + i * 4096 + t * 16);
        __syncthreads();
        #pragma unroll
        for (int k2 = 0; k2 < 2; ++k2) {
            f16x8 af[4], bf[4];
            int kByte = k2 * 64 + (lane >> 4) * 16;
            #pragma unroll
            for (int mi = 0; mi < 4; ++mi) {
                int row = wm + mi * 16 + (lane & 15);
                af[mi] = *(const f16x8*)(As + ((row * 128 + kByte) ^ ((row & 7) << 4)));
            }
            #pragma unroll
            for (int ni = 0; ni < 4; ++ni) {
                int row = wn + ni * 16 + (lane & 15);
                bf[ni] = *(const f16x8*)(Bs + ((row * 128 + kByte) ^ ((row & 7) << 4)));
            }
            #pragma unroll
            for (int mi = 0; mi < 4; ++mi)
                #pragma unroll
                for (int ni = 0; ni < 4; ++ni)
                    acc[mi][ni] = __builtin_amdgcn_mfma_f32_16x16x32_f16(af[mi], bf[ni], acc[mi][ni], 0, 0, 0);
        }
    }
    int row0 = by * 128 + wm + ((lane >> 4) << 2);
    int col0 = bx * 128 + wn + (lane & 15);
    size_t outBase = (size_t)z * (AW * BH);
    #pragma unroll
    for (int mi = 0; mi < 4; ++mi)
        #pragma unroll
        for (int ni = 0; ni < 4; ++ni)
            #pragma unroll
            for (int r = 0; r < 4; ++r)
                outP[outBase + (size_t)(row0 + mi * 16 + r) * BH + col0 + ni * 16] = acc[mi][ni][r];
}

// ---------------- launch ----------------
extern "C" void kernel_launch(void* const* d_in, const int* in_sizes, int n_in,
                              void* d_out, int out_size, void* d_ws, size_t ws_size,
                              hipStream_t stream) {
    const float* x     = (const float*)d_in[0];
    const float* A_ref = (const float*)d_in[1];
    const float* B_ref = (const float*)d_in[2];
    const float* sA    = (const float*)d_in[3];
    const float* sB    = (const float*)d_in[4];
    float* out = (float*)d_out;
    char* ws = (char*)d_ws;

    const int nA = AW * AH;  const unsigned jA = (unsigned)(nA / 2);
    const int nB = BW * BH;  const unsigned jB = (unsigned)(nB / 2);
    const int nx8 = (BATCH * CDIM * HW) / 8;
    const int outElems = BATCH * AW * BH;  // 16,777,216 f32 (= 67.1MB, exactly xf16's size)

    _Float16* Am     = (_Float16*)(ws + 0);          // [1024][4096] f16
    _Float16* BmT    = (_Float16*)(ws + 8388608);    // [512][256]  f16
    _Float16* temp   = (_Float16*)(ws + 8650752);    // [32][1024][256] f16
    unsigned* scratch= (unsigned*)(ws + 25427968);

    // x (f16) overlays the d_out "out" region; gemm2 overwrites it only after gemm1 consumed it
    _Float16* xf16 = (_Float16*)d_out;

    hipMemsetAsync(scratch, 0, MEMSET_U32 * 4, stream);

    // ---- mask pipeline (finalize folded into apply); x cvt rides the last pre-GEMM dispatch ----
    hist0_kernel<<<dim3(256, 2), 256, 0, stream>>>(sA, nA, sB, nB, scratch);
    hist1_kernel<<<dim3(256, 2), 256, 0, stream>>>(sA, nA, jA, sB, nB, jB, scratch);
    extract_kernel<<<dim3(256, 2), 256, 0, stream>>>(sA, nA, jA, sB, nB, jB, scratch);
    apply_cvt_kernel<<<dim3(1024, 6), 256, 0, stream>>>(sA, A_ref, Am, out + outElems,
                                                        sB, B_ref, BmT, out + outElems + nA,
                                                        nA, nB, x, xf16, nx8, scratch);

    // ---- GEMM1 (m97-exact, both operands f16 gload_lds, XCD-local x reuse) ----
    gemm1_kernel<<<512, 256, 0, stream>>>(Am, xf16, temp);

    // ---- GEMM2 (single-buffer, XCD-grouped temp reuse) ----
    gemm2_kernel<<<1024, 256, 0, stream>>>(temp, BmT, out);
}

// Round 11
// 182.297 us; speedup vs baseline: 1.1213x; 1.0293x over previous
//
#include <hip/hip_runtime.h>

typedef _Float16 f16x8 __attribute__((ext_vector_type(8)));
typedef _Float16 f16x4 __attribute__((ext_vector_type(4)));
typedef float    f32x4 __attribute__((ext_vector_type(4)));

static constexpr int BATCH = 32;
static constexpr int CDIM  = 256;    // C
static constexpr int HW    = 4096;   // h (= A_H = K of GEMM1)
static constexpr int AW    = 1024;   // A rows (w)
static constexpr int AH    = 4096;   // A cols (h)
static constexpr int BW    = 256;    // B rows (c)
static constexpr int BH    = 512;    // B cols (d)
static constexpr int CAND_CAP = 8192;

// scratch u32 layout (relative to scratch base)
// 0     histA0[4096]   4096  histA1[4096]
// 8192  histB0[4096]   12288 histB1[4096]
// 16384 selA[8]  ([3]=target2 [6]=candCount)   16392 selB[8]
// 16400 candBitsA[8192]  24592 candIdxA[8192]
// 32784 candBitsB[8192]  40976 candIdxB[8192]
static constexpr int MEMSET_U32 = 16400;

__device__ __forceinline__ void gload16(const void* g, void* l) {
    __builtin_amdgcn_global_load_lds((const __attribute__((address_space(1))) void*)g,
                                     (__attribute__((address_space(3))) void*)l, 16, 0, 0);
}

// every block computes the same select result from a global 4096-bin histogram.
__device__ void select_bin_inline(const unsigned* __restrict__ hist, unsigned target,
                                  unsigned* shp /*[256]*/, unsigned* res /*[2]*/) {
    const int t = threadIdx.x;
    unsigned sum = 0;
    #pragma unroll
    for (int k = 0; k < 16; ++k) sum += hist[t * 16 + k];
    shp[t] = sum;
    __syncthreads();
    if (t == 0) {
        unsigned c = 0; int k = 0;
        while (c + shp[k] <= target) { c += shp[k]; ++k; }
        int b = k * 16;
        while (true) { unsigned h = hist[b]; if (target < c + h) break; c += h; ++b; }
        res[0] = (unsigned)b; res[1] = c;
    }
    __syncthreads();
}

// ---------------- pass 0: hist of key>>19 (12 bits), per-wave LDS hist ----------------
__global__ void hist0_kernel(const float* __restrict__ sA, int nA,
                             const float* __restrict__ sB, int nB,
                             unsigned* __restrict__ scratch) {
    __shared__ unsigned lh[4][4096];
    const int y = blockIdx.y;
    const int t = threadIdx.x;
    const float* s = y ? sB : sA;
    const int n4 = (y ? nB : nA) >> 2;
    unsigned* hist = scratch + (y ? 8192 : 0);
    const int wave = t >> 6;
    for (int i = t; i < 4 * 4096; i += 256) ((unsigned*)lh)[i] = 0;
    __syncthreads();
    for (int i = blockIdx.x * 256 + t; i < n4; i += gridDim.x * 256) {
        float4 v = reinterpret_cast<const float4*>(s)[i];
        atomicAdd(&lh[wave][(__float_as_uint(v.x) & 0x7fffffffu) >> 19], 1u);
        atomicAdd(&lh[wave][(__float_as_uint(v.y) & 0x7fffffffu) >> 19], 1u);
        atomicAdd(&lh[wave][(__float_as_uint(v.z) & 0x7fffffffu) >> 19], 1u);
        atomicAdd(&lh[wave][(__float_as_uint(v.w) & 0x7fffffffu) >> 19], 1u);
    }
    __syncthreads();
    for (int b = t; b < 4096; b += 256) {
        unsigned v = lh[0][b] + lh[1][b] + lh[2][b] + lh[3][b];
        if (v) atomicAdd(&hist[b], v);
    }
}

// ---------------- pass 1: inline select0, hist of (key>>7)&4095 among prefix matches ----------------
__global__ void hist1_kernel(const float* __restrict__ sA, int nA, unsigned jA,
                             const float* __restrict__ sB, int nB, unsigned jB,
                             unsigned* __restrict__ scratch) {
    __shared__ unsigned lh[4][4096];
    __shared__ unsigned shp[256];
    __shared__ unsigned res[2];
    const int y = blockIdx.y;
    const float* s = y ? sB : sA;
    const int n4 = (y ? nB : nA) >> 2;
    const unsigned j = y ? jB : jA;
    const unsigned* hist0 = scratch + (y ? 8192 : 0);
    unsigned* hist1 = scratch + 4096 + (y ? 8192 : 0);
    const int t = threadIdx.x;
    const int wave = t >> 6;
    for (int i = t; i < 4 * 4096; i += 256) ((unsigned*)lh)[i] = 0;
    select_bin_inline(hist0, j, shp, res);       // includes syncthreads
    const unsigned bin0 = res[0];
    for (int i = blockIdx.x * 256 + t; i < n4; i += gridDim.x * 256) {
        float4 v = reinterpret_cast<const float4*>(s)[i];
        unsigned k0 = __float_as_uint(v.x) & 0x7fffffffu;
        unsigned k1 = __float_as_uint(v.y) & 0x7fffffffu;
        unsigned k2 = __float_as_uint(v.z) & 0x7fffffffu;
        unsigned k3 = __float_as_uint(v.w) & 0x7fffffffu;
        if ((k0 >> 19) == bin0) atomicAdd(&lh[wave][(k0 >> 7) & 4095], 1u);
        if ((k1 >> 19) == bin0) atomicAdd(&lh[wave][(k1 >> 7) & 4095], 1u);
        if ((k2 >> 19) == bin0) atomicAdd(&lh[wave][(k2 >> 7) & 4095], 1u);
        if ((k3 >> 19) == bin0) atomicAdd(&lh[wave][(k3 >> 7) & 4095], 1u);
    }
    __syncthreads();
    for (int b = t; b < 4096; b += 256) {
        unsigned v = lh[0][b] + lh[1][b] + lh[2][b] + lh[3][b];
        if (v) atomicAdd(&hist1[b], v);
    }
}

// ---------------- extract: inline select0+select1, gather candidates with 24-bit prefix ----------------
__global__ void extract_kernel(const float* __restrict__ sA, int nA, unsigned jA,
                               const float* __restrict__ sB, int nB, unsigned jB,
                               unsigned* __restrict__ scratch) {
    __shared__ unsigned shp[256];
    __shared__ unsigned res0[2], res1[2];
    const int y = blockIdx.y;
    const float* s = y ? sB : sA;
    const int n4 = (y ? nB : nA) >> 2;
    const unsigned j = y ? jB : jA;
    const unsigned* hist0 = scratch + (y ? 8192 : 0);
    const unsigned* hist1 = scratch + 4096 + (y ? 8192 : 0);
    unsigned* sel = scratch + 16384 + y * 8;
    unsigned* candBits = scratch + (y ? 32784 : 16400);
    unsigned* candIdx  = candBits + CAND_CAP;
    const int t = threadIdx.x;
    select_bin_inline(hist0, j, shp, res0);
    select_bin_inline(hist1, j - res0[1], shp, res1);
    const unsigned pref = (res0[0] << 12) | res1[0];
    const unsigned base2 = res0[1] + res1[1];
    if (blockIdx.x == 0 && t == 0) sel[3] = j - base2;   // rank within candidate set
    for (int i = blockIdx.x * 256 + t; i < n4; i += gridDim.x * 256) {
        float4 v = reinterpret_cast<const float4*>(s)[i];
        #pragma unroll
        for (int k = 0; k < 4; ++k) {
            unsigned bits = __float_as_uint(k == 0 ? v.x : k == 1 ? v.y : k == 2 ? v.z : v.w) & 0x7fffffffu;
            if ((bits >> 7) == pref) {
                unsigned p = atomicAdd(&sel[6], 1u);
                if (p < CAND_CAP) { candBits[p] = bits; candIdx[p] = (unsigned)(i * 4 + k); }
            }
        }
    }
}

// -------- apply + cvt (+ inline finalize): y=0 A-mask, y=1 B-mask, y=2..5 x f32->f16 slabs -------
__global__ void apply_cvt_kernel(const float* __restrict__ sA, const float* __restrict__ wA,
                                 _Float16* __restrict__ Am, float* __restrict__ wcopyA,
                                 const float* __restrict__ sB, const float* __restrict__ wB,
                                 _Float16* __restrict__ BmT, float* __restrict__ wcopyB,
                                 int nA, int nB,
                                 const float* __restrict__ x, _Float16* __restrict__ xf, int nx8,
                                 const unsigned* __restrict__ scratch) {
    const int y = blockIdx.y;
    const int t = threadIdx.x;
    if (y >= 2) {
        int vb = (y - 2) * gridDim.x + blockIdx.x;
        int stride = 4 * gridDim.x * 256;
        for (int i = vb * 256 + t; i < nx8; i += stride) {
            f32x4 v0 = reinterpret_cast<const f32x4*>(x)[i * 2];
            f32x4 v1 = reinterpret_cast<const f32x4*>(x)[i * 2 + 1];
            f16x8 h = { (_Float16)v0[0], (_Float16)v0[1], (_Float16)v0[2], (_Float16)v0[3],
                        (_Float16)v1[0], (_Float16)v1[1], (_Float16)v1[2], (_Float16)v1[3] };
            reinterpret_cast<f16x8*>(xf)[i] = h;
        }
        return;
    }
    // ---- inline finalize ----
    __shared__ unsigned s_vcut, s_cut;
    const unsigned* sel = scratch + 16384 + y * 8;
    const unsigned* candBits = scratch + (y ? 32784 : 16400);
    const unsigned* candIdx  = candBits + CAND_CAP;
    if (t == 0) { s_vcut = 0u; s_cut = 0u; }
    __syncthreads();
    {
        unsigned cnt = sel[6]; if (cnt > CAND_CAP) cnt = CAND_CAP;
        const unsigned target = sel[3];
        for (unsigned c = t; c < cnt; c += 256) {
            unsigned b = candBits[c], ix = candIdx[c];
            unsigned r = 0;
            for (unsigned q = 0; q < cnt; ++q) {
                unsigned bq = candBits[q];
                r += (bq < b) || (bq == b && candIdx[q] < ix);
            }
            if (r == target) { s_vcut = b; s_cut = ix; }
        }
    }
    __syncthreads();
    const unsigned vcut = s_vcut, cutIdx = s_cut;

    const float* s = y ? sB : sA;
    const float* w = y ? wB : wA;
    float* wcopy = y ? wcopyB : wcopyA;
    const int n4 = (y ? nB : nA) >> 2;
    for (int i = blockIdx.x * 256 + t; i < n4; i += gridDim.x * 256) {
        float4 sv = reinterpret_cast<const float4*>(s)[i];
        float4 wv = reinterpret_cast<const float4*>(w)[i];
        reinterpret_cast<float4*>(wcopy)[i] = wv;
        unsigned idx0 = (unsigned)i * 4;
        float m[4];
        #pragma unroll
        for (int k = 0; k < 4; ++k) {
            unsigned bits = __float_as_uint(k == 0 ? sv.x : k == 1 ? sv.y : k == 2 ? sv.z : sv.w) & 0x7fffffffu;
            bool keep = (bits > vcut) || (bits == vcut && (idx0 + k) >= cutIdx);
            m[k] = keep ? 1.0f : 0.0f;
        }
        if (!y) {
            f16x4 o = { (_Float16)(wv.x * m[0]), (_Float16)(wv.y * m[1]),
                        (_Float16)(wv.z * m[2]), (_Float16)(wv.w * m[3]) };
            *reinterpret_cast<f16x4*>(Am + idx0) = o;
        } else {
            int c = (int)(idx0 >> 9);           // row of B_ref [256][512]
            int d = (int)(idx0 & 511);
            BmT[(size_t)(d + 0) * BW + c] = (_Float16)(wv.x * m[0]);
            BmT[(size_t)(d + 1) * BW + c] = (_Float16)(wv.y * m[1]);
            BmT[(size_t)(d + 2) * BW + c] = (_Float16)(wv.z * m[2]);
            BmT[(size_t)(d + 3) * BW + c] = (_Float16)(wv.w * m[3]);
        }
    }
}

// ========== GEMM1 pipelined (T3+T4+T5): temp[b][w][c] = sum_h Am[w][h] * xf[b][c][h] ============
// BM=128 (w) x BN=256 (c), one block per (batch b, w-tile): grid 256 = 1 block/CU, 8 waves (512t),
// per-wave 64x64 output. 3-deep global_load_lds pipeline (3 LDS bufs x 48KB = 144KB), counted
// s_waitcnt vmcnt(6) at K-tile boundaries (6 = in-flight loads of tile k+2; NEVER 0 mid-loop),
// raw s_barrier (no compiler vmcnt(0) drain), 2 phases/K-tile with 16-MFMA setprio clusters.
// Correctness-critical point is ONLY the boundary: vmcnt(6)+barrier (tile k+1 staged; all waves
// done reading buf being rotated to stage target) with sched_barrier(0) pinning stage hoist.
// XCD-local x reuse: XCD k owns batches 4k..4k+3 (each x row-block read once into that XCD's L2).
__global__ __launch_bounds__(512) void gemm1_pipe_kernel(
        const _Float16* __restrict__ Am,   // [1024][4096] f16
        const _Float16* __restrict__ xf,   // [32][256][4096] f16
        _Float16* __restrict__ temp) {     // [32][1024][256] f16
    __shared__ __align__(16) char lds[147456];   // 3 x (A 16KB @0 + B 32KB @16384)
    const int t = threadIdx.x;
    const int lane = t & 63;
    const int wave = t >> 6;              // 0..7
    const int wm = (wave >> 2) * 64;      // 0,64   (M half)
    const int wn = (wave & 3) * 64;       // 0..192 (N quarter)
    const int xcd = blockIdx.x & 7;
    const int seq = blockIdx.x >> 3;      // 0..31
    const int bb  = xcd * 4 + (seq >> 3); // batch 0..31
    const int by  = seq & 7;              // w-tile 0..7

    // staging: A-tile 128x64 f16 = 1024 16B-chunks (2/thread); B-tile 256x64 = 2048 (4/thread)
    // chunk i: row = i*64 + (t>>3); kkPhys = t&7; source pre-swizzled: kkLog = (t&7) ^ (row&7)
    const int sRow = t >> 3;              // 0..63
    const int sKk  = (t & 7) ^ (sRow & 7);
    const _Float16* aSrc = Am + ((size_t)by * 128 + sRow) * HW + sKk * 8;
    const _Float16* xSrc = xf + ((size_t)bb * 256 + sRow) * HW + sKk * 8;

    // fragment-read constants: row&7 == lane&7 (wm/wn/mi*16 are multiples of 8)
    const int swz = (lane & 7) << 4;
    const int kb0 = (lane >> 4) << 4;     // 16B sub-chunk within 64B ksub

    f32x4 acc[4][4] = {};

    #define G1P_RD_A(buf, mi, ks) (*(const f16x8*)((buf) + \
        ((((wm + (mi)*16 + (lane & 15)) * 128) + (ks)*64 + kb0) ^ swz)))
    #define G1P_RD_B(buf, ni, ks) (*(const f16x8*)((buf) + 16384 + \
        ((((wn + (ni)*16 + (lane & 15)) * 128) + (ks)*64 + kb0) ^ swz)))

    // prologue: stage tiles 0,1 (12 loads in flight), wait for tile 0 (vmcnt(6))
    {
        char* b0 = lds;
        char* b1 = lds + 49152;
        #pragma unroll
        for (int i = 0; i < 2; ++i) gload16(aSrc + (size_t)i * 64 * HW, b0 + i * 8192 + t * 16);
        #pragma unroll
        for (int i = 0; i < 4; ++i) gload16(xSrc + (size_t)i * 64 * HW, b0 + 16384 + i * 8192 + t * 16);
        #pragma unroll
        for (int i = 0; i < 2; ++i) gload16(aSrc + 64 + (size_t)i * 64 * HW, b1 + i * 8192 + t * 16);
        #pragma unroll
        for (int i = 0; i < 4; ++i) gload16(xSrc + 64 + (size_t)i * 64 * HW, b1 + 16384 + i * 8192 + t * 16);
    }
    asm volatile("s_waitcnt vmcnt(6)" ::: "memory");
    __builtin_amdgcn_s_barrier();
    __builtin_amdgcn_sched_barrier(0);

    int rot0 = 0, rot1 = 49152, rot2 = 98304;   // cur, next, stage-target (tile k+2)
    for (int k = 0; k < 64; ++k) {
        char* cur = lds + rot0;
        char* stg = lds + rot2;
        const bool st = (k + 2) < 64;
        const int kof = (k + 2) * 64;
        f16x8 af[4][2], bf[4][2];
        // ---- phase 0: read af[0..1] + bf[0..3]; stage A(2) + B0 ----
        #pragma unroll
        for (int mi = 0; mi < 2; ++mi) {
            af[mi][0] = G1P_RD_A(cur, mi, 0);
            af[mi][1] = G1P_RD_A(cur, mi, 1);
        }
        #pragma unroll
        for (int ni = 0; ni < 4; ++ni) {
            bf[ni][0] = G1P_RD_B(cur, ni, 0);
            bf[ni][1] = G1P_RD_B(cur, ni, 1);
        }
        if (st) {
            gload16(aSrc + kof, stg + t * 16);
            gload16(aSrc + kof + (size_t)64 * HW, stg + 8192 + t * 16);
            gload16(xSrc + kof, stg + 16384 + t * 16);
        }
        __builtin_amdgcn_s_barrier();
        __builtin_amdgcn_s_setprio(1);
        #pragma unroll
        for (int ks = 0; ks < 2; ++ks)
            #pragma unroll
            for (int mi = 0; mi < 2; ++mi)
                #pragma unroll
                for (int ni = 0; ni < 4; ++ni)
                    acc[mi][ni] = __builtin_amdgcn_mfma_f32_16x16x32_f16(af[mi][ks], bf[ni][ks], acc[mi][ni], 0, 0, 0);
        __builtin_amdgcn_s_setprio(0);
        __builtin_amdgcn_s_barrier();
        // ---- phase 1: read af[2..3]; stage B1..B3 ----
        #pragma unroll
        for (int mi = 2; mi < 4; ++mi) {
            af[mi][0] = G1P_RD_A(cur, mi, 0);
            af[mi][1] = G1P_RD_A(cur, mi, 1);
        }
        if (st) {
            gload16(xSrc + kof + (size_t)64 * HW,  stg + 16384 + 8192 + t * 16);
            gload16(xSrc + kof + (size_t)128 * HW, stg + 16384 + 16384 + t * 16);
            gload16(xSrc + kof + (size_t)192 * HW, stg + 16384 + 24576 + t * 16);
        }
        __builtin_amdgcn_s_barrier();
        __builtin_amdgcn_s_setprio(1);
        #pragma unroll
        for (int ks = 0; ks < 2; ++ks)
            #pragma unroll
            for (int mi = 2; mi < 4; ++mi)
                #pragma unroll
                for (int ni = 0; ni < 4; ++ni)
                    acc[mi][ni] = __builtin_amdgcn_mfma_f32_16x16x32_f16(af[mi][ks], bf[ni][ks], acc[mi][ni], 0, 0, 0);
        __builtin_amdgcn_s_setprio(0);
        // ---- K-tile boundary: tile k+1 must be resident; tile k+2's 6 loads stay in flight ----
        if (st)            { asm volatile("s_waitcnt vmcnt(6)" ::: "memory"); }
        else if (k < 63)   { asm volatile("s_waitcnt vmcnt(0)" ::: "memory"); }
        __builtin_amdgcn_s_barrier();
        __builtin_amdgcn_sched_barrier(0);
        int tmp = rot0; rot0 = rot1; rot1 = rot2; rot2 = tmp;
    }

    // epilogue: temp[bb][gw][c]
    size_t outBase = (size_t)bb * (AW * CDIM);
    int row0 = by * 128 + wm + ((lane >> 4) << 2);
    int col0 = wn + (lane & 15);
    #pragma unroll
    for (int mi = 0; mi < 4; ++mi)
        #pragma unroll
        for (int ni = 0; ni < 4; ++ni)
            #pragma unroll
            for (int r = 0; r < 4; ++r) {
                int gw = row0 + mi * 16 + r;
                int c  = col0 + ni * 16;
                temp[outBase + (size_t)gw * CDIM + c] = (_Float16)acc[mi][ni][r];
            }
}

// ---------------- GEMM2 (single-buffer, XCD-grouped): out[b][w][d] = sum_c temp*BmT --------------
__global__ __launch_bounds__(256) void gemm2_kernel(
        const _Float16* __restrict__ A,    // temp [32][1024][256]
        const _Float16* __restrict__ B,    // BmT  [512][256]
        float* __restrict__ outP) {        // out  [32][1024][512]
    __shared__ __align__(16) char lds[32768];
    char* As = lds;
    char* Bs = lds + 16384;
    const int t = threadIdx.x;
    const int lane = t & 63;
    const int wave = t >> 6;
    const int wm = (wave >> 1) * 64;
    const int wn = (wave & 1) * 64;
    constexpr int K = CDIM;            // 256

    const int l  = (blockIdx.x & 7) * 128 + (blockIdx.x >> 3);
    const int bx = l & 3;              // d-tile 0..3
    const int by = (l >> 2) & 7;       // w-tile 0..7
    const int z  = l >> 5;             // batch 0..31

    const int r0 = t >> 3;
    const int kk = t & 7;
    const int kkSwz = kk ^ (r0 & 7);
    const _Float16* aSrc = A + (size_t)z * (AW * CDIM) + ((size_t)by * 128 + r0) * K + kkSwz * 8;
    const _Float16* bSrc = B + ((size_t)bx * 128 + r0) * K + kkSwz * 8;
    f32x4 acc[4][4] = {};
    for (int kt = 0; kt < K; kt += 64) {
        __syncthreads();
        #pragma unroll
        for (int i = 0; i < 4; ++i)
            gload16(aSrc + kt + (size_t)i * 32 * K, As + i * 4096 + t * 16);
        #pragma unroll
        for (int i = 0; i < 4; ++i)
            gload16(bSrc + kt + (size_t)i * 32 * K, Bs + i * 4096 + t * 16);
        __syncthreads();
        #pragma unroll
        for (int k2 = 0; k2 < 2; ++k2) {
            f16x8 af[4], bf[4];
            int kByte = k2 * 64 + (lane >> 4) * 16;
            #pragma unroll
            for (int mi = 0; mi < 4; ++mi) {
                int row = wm + mi * 16 + (lane & 15);
                af[mi] = *(const f16x8*)(As + ((row * 128 + kByte) ^ ((row & 7) << 4)));
            }
            #pragma unroll
            for (int ni = 0; ni < 4; ++ni) {
                int row = wn + ni * 16 + (lane & 15);
                bf[ni] = *(const f16x8*)(Bs + ((row * 128 + kByte) ^ ((row & 7) << 4)));
            }
            #pragma unroll
            for (int mi = 0; mi < 4; ++mi)
                #pragma unroll
                for (int ni = 0; ni < 4; ++ni)
                    acc[mi][ni] = __builtin_amdgcn_mfma_f32_16x16x32_f16(af[mi], bf[ni], acc[mi][ni], 0, 0, 0);
        }
    }
    int row0 = by * 128 + wm + ((lane >> 4) << 2);
    int col0 = bx * 128 + wn + (lane & 15);
    size_t outBase = (size_t)z * (AW * BH);
    #pragma unroll
    for (int mi = 0; mi < 4; ++mi)
        #pragma unroll
        for (int ni = 0; ni < 4; ++ni)
            #pragma unroll
            for (int r = 0; r < 4; ++r)
                outP[outBase + (size_t)(row0 + mi * 16 + r) * BH + col0 + ni * 16] = acc[mi][ni][r];
}

// ---------------- launch ----------------
extern "C" void kernel_launch(void* const* d_in, const int* in_sizes, int n_in,
                              void* d_out, int out_size, void* d_ws, size_t ws_size,
                              hipStream_t stream) {
    const float* x     = (const float*)d_in[0];
    const float* A_ref = (const float*)d_in[1];
    const float* B_ref = (const float*)d_in[2];
    const float* sA    = (const float*)d_in[3];
    const float* sB    = (const float*)d_in[4];
    float* out = (float*)d_out;
    char* ws = (char*)d_ws;

    const int nA = AW * AH;  const unsigned jA = (unsigned)(nA / 2);
    const int nB = BW * BH;  const unsigned jB = (unsigned)(nB / 2);
    const int nx8 = (BATCH * CDIM * HW) / 8;
    const int outElems = BATCH * AW * BH;  // 16,777,216 f32 (= 67.1MB, exactly xf16's size)

    _Float16* Am     = (_Float16*)(ws + 0);          // [1024][4096] f16
    _Float16* BmT    = (_Float16*)(ws + 8388608);    // [512][256]  f16
    _Float16* temp   = (_Float16*)(ws + 8650752);    // [32][1024][256] f16
    unsigned* scratch= (unsigned*)(ws + 25427968);

    // x (f16) overlays the d_out "out" region; gemm2 overwrites it only after gemm1 consumed it
    _Float16* xf16 = (_Float16*)d_out;

    hipMemsetAsync(scratch, 0, MEMSET_U32 * 4, stream);

    // ---- mask pipeline (finalize folded into apply); x cvt rides the last pre-GEMM dispatch ----
    hist0_kernel<<<dim3(256, 2), 256, 0, stream>>>(sA, nA, sB, nB, scratch);
    hist1_kernel<<<dim3(256, 2), 256, 0, stream>>>(sA, nA, jA, sB, nB, jB, scratch);
    extract_kernel<<<dim3(256, 2), 256, 0, stream>>>(sA, nA, jA, sB, nB, jB, scratch);
    apply_cvt_kernel<<<dim3(1024, 6), 256, 0, stream>>>(sA, A_ref, Am, out + outElems,
                                                        sB, B_ref, BmT, out + outElems + nA,
                                                        nA, nB, x, xf16, nx8, scratch);

    // ---- GEMM1 (pipelined: counted vmcnt, raw barriers, setprio clusters) ----
    gemm1_pipe_kernel<<<256, 512, 0, stream>>>(Am, xf16, temp);

    // ---- GEMM2 (single-buffer, XCD-grouped temp reuse) ----
    gemm2_kernel<<<1024, 256, 0, stream>>>(temp, BmT, out);
}